// Round 2
// baseline (3796.948 us; speedup 1.0000x reference)
//
#include <hip/hip_runtime.h>
#include <hip/hip_bf16.h>

// LSNN adaptive-LIF scan, T=1000, B=64, N_in=256, N_h=512, fp32.
//   1) F = X @ w_in.T precomputed by a tiled fp32 GEMM (chunked through ws).
//   2) Scan: 64 WGs (one per batch element) x 512 threads (one neuron per
//      thread). Recurrent term exploits binary z: deterministic
//      ballot-compaction of active neurons -> sparse column adds from
//      transposed w_rec (coalesced 256B/wave reads, L2-resident).
// State-update arithmetic uses __f*_rn intrinsics to forbid fma contraction
// (must match numpy's separate mul/add rounding — spikes are binary and
// compared exactly).

#define TT   1000
#define BB   64
#define NIN  256
#define NH   512

// exact f32 constants as Python would produce them (f64 math, one rounding)
__device__ constexpr float KV = (float)(0.001 * 100.0);            // DT*TAU_MEM_INV
__device__ constexpr float KI = (float)(0.001 * 200.0);            // DT*TAU_SYN_INV
__device__ constexpr float KB = (float)(0.001 * (1.0 / 800.0));    // DT*TAU_ADAPT_INV
__device__ constexpr float KJ = (float)((1.0 / 800.0) * 1.8);      // TAU_ADAPT_INV*BETA

// ---------------- transpose w_rec (512x512): wT[j][n] = w_rec[n][j] ----------
__global__ void transp512(const float* __restrict__ in, float* __restrict__ ot) {
    __shared__ float tile[32][33];
    const int tx = threadIdx.x;            // 0..31
    const int ty = threadIdx.y;            // 0..7
    const int jcol = blockIdx.x * 32 + tx; // source col
    const int row0 = blockIdx.y * 32;      // source row base
    for (int r = ty; r < 32; r += 8)
        tile[r][tx] = in[(size_t)(row0 + r) * NH + jcol];
    __syncthreads();
    const int ncol = blockIdx.y * 32 + tx; // dest col (= source row)
    const int jrow0 = blockIdx.x * 32;     // dest row base (= source col)
    for (int r = ty; r < 32; r += 8)
        ot[(size_t)(jrow0 + r) * NH + ncol] = tile[tx][r];
}

// ---------------- fp32 GEMM: F[m][n] = sum_k X[m][k] * W[n][k] ---------------
// M = chunk rows (multiple of 128), N = 512, K = 256.
__global__ __launch_bounds__(256)
void gemm_ff(const float* __restrict__ X, const float* __restrict__ W,
             float* __restrict__ F, int M) {
    const int bx = blockIdx.x;   // n-tile: 0..3
    const int by = blockIdx.y;   // m-tile
    const int tid = threadIdx.x;

    __shared__ float As[32][128];
    __shared__ float Bs[32][128];

    const int tn0 = (tid & 15) * 8;
    const int tm0 = (tid >> 4) * 8;
    float acc[8][8] = {};

    const int am = tid >> 1;             // 0..127: row within tile
    const int aq = (tid & 1) * 4;        // float4 group base within BK=32

    const float* Xb = X + (size_t)(by * 128 + am) * NIN;
    const float* Wb = W + (size_t)(bx * 128 + am) * NIN;

    for (int k0 = 0; k0 < NIN; k0 += 32) {
        __syncthreads();
#pragma unroll
        for (int i2 = 0; i2 < 4; ++i2) {
            const int q = aq + i2;       // 0..7
            float4 xa = *reinterpret_cast<const float4*>(Xb + k0 + q * 4);
            As[q * 4 + 0][am] = xa.x; As[q * 4 + 1][am] = xa.y;
            As[q * 4 + 2][am] = xa.z; As[q * 4 + 3][am] = xa.w;
            float4 wa = *reinterpret_cast<const float4*>(Wb + k0 + q * 4);
            Bs[q * 4 + 0][am] = wa.x; Bs[q * 4 + 1][am] = wa.y;
            Bs[q * 4 + 2][am] = wa.z; Bs[q * 4 + 3][am] = wa.w;
        }
        __syncthreads();
#pragma unroll 8
        for (int kk = 0; kk < 32; ++kk) {
            float4 a0 = *reinterpret_cast<const float4*>(&As[kk][tm0]);
            float4 a1 = *reinterpret_cast<const float4*>(&As[kk][tm0 + 4]);
            float4 b0 = *reinterpret_cast<const float4*>(&Bs[kk][tn0]);
            float4 b1 = *reinterpret_cast<const float4*>(&Bs[kk][tn0 + 4]);
            const float av[8] = {a0.x, a0.y, a0.z, a0.w, a1.x, a1.y, a1.z, a1.w};
            const float bv[8] = {b0.x, b0.y, b0.z, b0.w, b1.x, b1.y, b1.z, b1.w};
#pragma unroll
            for (int i = 0; i < 8; ++i)
#pragma unroll
                for (int j = 0; j < 8; ++j)
                    acc[i][j] += av[i] * bv[j];
        }
    }

    float* Fo = F + (size_t)(by * 128 + tm0) * NH + bx * 128 + tn0;
#pragma unroll
    for (int i = 0; i < 8; ++i) {
        *reinterpret_cast<float4*>(Fo + (size_t)i * NH) =
            make_float4(acc[i][0], acc[i][1], acc[i][2], acc[i][3]);
        *reinterpret_cast<float4*>(Fo + (size_t)i * NH + 4) =
            make_float4(acc[i][4], acc[i][5], acc[i][6], acc[i][7]);
    }
}

// ---------------- scan kernel: one WG per batch element ----------------------
// st layout: [z | v | i | b], each BB*NH floats.
__global__ __launch_bounds__(512, 1)
void lsnn_scan(const float* __restrict__ F, const float* __restrict__ wT,
               const float* __restrict__ z0, const float* __restrict__ v0,
               const float* __restrict__ i0, const float* __restrict__ b0,
               float* __restrict__ out, float* __restrict__ st,
               int t0, int Tc, int first, int last) {
    const int n = threadIdx.x;          // neuron 0..511
    const int b = blockIdx.x;           // batch 0..63
    const int lane = n & 63;
    const int wv = n >> 6;              // wave id 0..7
    const size_t bn = (size_t)b * NH + n;

    __shared__ __align__(16) int lists[2][NH];
    __shared__ int cnts[2][8];

    float v, cur, bb, zprev;
    if (first) {
        zprev = z0[bn]; v = v0[bn]; cur = i0[bn]; bb = b0[bn];
    } else {
        zprev = st[0 * BB * NH + bn];
        v     = st[1 * BB * NH + bn];
        cur   = st[2 * BB * NH + bn];
        bb    = st[3 * BB * NH + bn];
    }

    // build initial active list (par=0) from zprev, ascending neuron order
    int cnt;
    {
        unsigned long long m = __ballot(zprev > 0.0f);
        if (lane == 0) cnts[0][wv] = __popcll(m);
        __syncthreads();
        int base = 0, tot = 0;
        for (int q = 0; q < 8; ++q) {
            int c = cnts[0][q];
            if (q < wv) base += c;
            tot += c;
        }
        if (zprev > 0.0f)
            lists[0][base + __popcll(m & ((1ull << lane) - 1ull))] = n;
        __syncthreads();
        cnt = tot;                      // every thread computed tot identically
    }
    int par = 0;

    const float* wn = wT + n;                                   // column base
    const float* Fp = F + (size_t)b * NH + n;                   // + t*BB*NH
    float* op = out + ((size_t)t0 * BB + b) * NH + n;

    for (int t = 0; t < Tc; ++t) {
        // elementwise update — single-rounded ops, no fma contraction,
        // association matches numpy's elementwise evaluation
        const float v_dec = __fadd_rn(v,  __fmul_rn(KV, __fadd_rn(__fsub_rn(0.0f, v), cur)));
        const float i_dec = __fsub_rn(cur, __fmul_rn(KI, cur));
        const float b_dec = __fadd_rn(bb, __fmul_rn(KB, __fsub_rn(1.0f, bb)));
        const float zn = (__fsub_rn(v_dec, b_dec)) > 0.0f ? 1.0f : 0.0f;
        v  = (zn > 0.0f) ? 0.0f : v_dec;
        bb = __fadd_rn(b_dec, __fmul_rn(zn, KJ));
        *op = zn;
        op += (size_t)BB * NH;

        // ballot for the *new* list early (double-buffered)
        const unsigned long long mm = __ballot(zn > 0.0f);
        if (lane == 0) cnts[par ^ 1][wv] = __popcll(mm);

        // recurrent sum from previous step's spikes (lists[par]), own
        // accumulator so final add order is (i_dec + ff) + rec like numpy
        float rec = 0.0f;
        const int* lp = lists[par];
        int k = 0;
        for (; k + 8 <= cnt; k += 8) {
            int4 ja = *reinterpret_cast<const int4*>(lp + k);
            int4 jb = *reinterpret_cast<const int4*>(lp + k + 4);
            const float a0 = wn[(size_t)ja.x * NH];
            const float a1 = wn[(size_t)ja.y * NH];
            const float a2 = wn[(size_t)ja.z * NH];
            const float a3 = wn[(size_t)ja.w * NH];
            const float a4 = wn[(size_t)jb.x * NH];
            const float a5 = wn[(size_t)jb.y * NH];
            const float a6 = wn[(size_t)jb.z * NH];
            const float a7 = wn[(size_t)jb.w * NH];
            rec = __fadd_rn(rec, a0); rec = __fadd_rn(rec, a1);
            rec = __fadd_rn(rec, a2); rec = __fadd_rn(rec, a3);
            rec = __fadd_rn(rec, a4); rec = __fadd_rn(rec, a5);
            rec = __fadd_rn(rec, a6); rec = __fadd_rn(rec, a7);
        }
        for (; k < cnt; ++k) rec = __fadd_rn(rec, wn[(size_t)lp[k] * NH]);
        cur = __fadd_rn(__fadd_rn(i_dec, Fp[(size_t)t * BB * NH]), rec);

        __syncthreads();   // cnts[par^1] written by all waves; lists[par] drained

        int base = 0, tot = 0;
        for (int q = 0; q < 8; ++q) {
            int c = cnts[par ^ 1][q];
            if (q < wv) base += c;
            tot += c;
        }
        if (zn > 0.0f)
            lists[par ^ 1][base + __popcll(mm & ((1ull << lane) - 1ull))] = n;
        __syncthreads();   // lists[par^1] ready for next iteration

        par ^= 1;
        cnt = tot;
        zprev = zn;
    }

    // persist state for the next chunk
    st[0 * BB * NH + bn] = zprev;
    st[1 * BB * NH + bn] = v;
    st[2 * BB * NH + bn] = cur;
    st[3 * BB * NH + bn] = bb;

    if (last) {
        float* tail = out + (size_t)TT * BB * NH;
        tail[0 * BB * NH + bn] = zprev;  // zT
        tail[1 * BB * NH + bn] = v;      // vT
        tail[2 * BB * NH + bn] = cur;    // iT
        tail[3 * BB * NH + bn] = bb;     // bT
    }
}

// ---------------------------------------------------------------------------
extern "C" void kernel_launch(void* const* d_in, const int* in_sizes, int n_in,
                              void* d_out, int out_size, void* d_ws, size_t ws_size,
                              hipStream_t stream) {
    const float* X     = (const float*)d_in[0];
    const float* z0    = (const float*)d_in[1];
    const float* v0    = (const float*)d_in[2];
    const float* i0    = (const float*)d_in[3];
    const float* b0    = (const float*)d_in[4];
    const float* w_in  = (const float*)d_in[5];
    const float* w_rec = (const float*)d_in[6];
    float* out = (float*)d_out;

    char* ws = (char*)d_ws;
    float* wT = (float*)ws;                                    // 1 MB
    float* st = (float*)(ws + (1u << 20));                     // 512 KB
    char*  fbase = ws + (1u << 20) + (512u << 10);

    // chunk length in time steps, even, sized to fit two F buffers in ws
    const long long per = (long long)BB * NH * 4;              // bytes per step of F
    long long avail = (long long)ws_size - ((1ll << 20) + (512ll << 10));
    int Tc;
    if (avail >= 2 * per * TT) {
        Tc = TT;
    } else {
        Tc = (int)(avail / (2 * per));
        if (Tc > TT) Tc = TT;
        Tc &= ~1;
        if (Tc < 2) Tc = 2;   // assume ws_size is at least a few MB
    }
    const size_t fbytes = (size_t)Tc * per;
    float* Fb[2] = { (float*)fbase, (float*)(fbase + fbytes) };

    transp512<<<dim3(16, 16), dim3(32, 8), 0, stream>>>(w_rec, wT);

    int t0 = 0, buf = 0;
    bool firstc = true;
    while (t0 < TT) {
        const int Tcur = (Tc < TT - t0) ? Tc : (TT - t0);
        const int Mc = Tcur * BB;   // multiple of 128 (Tcur even)
        gemm_ff<<<dim3(4, Mc / 128), 256, 0, stream>>>(
            X + (size_t)t0 * BB * NIN, w_in, Fb[buf], Mc);
        lsnn_scan<<<dim3(BB), dim3(NH), 0, stream>>>(
            Fb[buf], wT, z0, v0, i0, b0, out, st,
            t0, Tcur, firstc ? 1 : 0, (t0 + Tcur >= TT) ? 1 : 0);
        firstc = false;
        buf ^= 1;
        t0 += Tcur;
    }
}

// Round 5
// 3397.309 us; speedup vs baseline: 1.1176x; 1.1176x over previous
//
#include <hip/hip_runtime.h>
#include <hip/hip_bf16.h>

// LSNN adaptive-LIF scan, T=1000, B=64, N_in=256, N_h=512, fp32.
//
// BITWISE CONSTRAINT (learned rounds 2-4): the harness compares binary spikes
// exactly; flips cascade. numpy/OpenBLAS reduces k sequentially ascending, so
// the recurrent term for column n MUST be one serial ascending-index
// __fadd_rn chain over active neurons (fma(0,w,c)=c, fma(1,w,c)=add(c,w) =>
// sparse ascending == dense BLAS, bitwise). No partial sums. Parallelism only
// across columns/batches; speed comes from latency hiding:
//   - software-pipelined gather (double-buffered 32-element register tiles:
//     issue tile k+1 loads before chaining tile k adds),
//   - byte-offset lists + int4 LDS reads,
//   - list padded with offsets to a zeroed wT row -> unconditional tiles
//     (x + (+0.0) is a bitwise no-op; an RN chain never yields -0.0),
//   - F prefetch at step top.
// Protocol is round-2's proven 2-barrier double-buffered-list scheme.

#define TT   1000
#define BB   64
#define NIN  256
#define NH   512
#define TS   32                          // gather tile size
#define PADOFF (NH * 2048)               // byte offset of zeroed row 512 of wT

__device__ constexpr float KV = (float)(0.001 * 100.0);            // DT*TAU_MEM_INV
__device__ constexpr float KI = (float)(0.001 * 200.0);            // DT*TAU_SYN_INV
__device__ constexpr float KB = (float)(0.001 * (1.0 / 800.0));    // DT*TAU_ADAPT_INV
__device__ constexpr float KJ = (float)((1.0 / 800.0) * 1.8);      // TAU_ADAPT_INV*BETA

// ---------------- transpose w_rec (512x512): wT[j][n] = w_rec[n][j] ----------
__global__ void transp512(const float* __restrict__ in, float* __restrict__ ot) {
    __shared__ float tile[32][33];
    const int tx = threadIdx.x;            // 0..31
    const int ty = threadIdx.y;            // 0..7
    const int jcol = blockIdx.x * 32 + tx;
    const int row0 = blockIdx.y * 32;
    for (int r = ty; r < 32; r += 8)
        tile[r][tx] = in[(size_t)(row0 + r) * NH + jcol];
    __syncthreads();
    const int ncol = blockIdx.y * 32 + tx;
    const int jrow0 = blockIdx.x * 32;
    for (int r = ty; r < 32; r += 8)
        ot[(size_t)(jrow0 + r) * NH + ncol] = tile[tx][r];
}

// zero row 512 of wT (padding target for unconditional gather tiles)
__global__ void zrow(float* __restrict__ wT) {
    wT[(size_t)NH * NH + threadIdx.x] = 0.0f;
}

// ---------------- fp32 GEMM: F[m][n] = sum_k X[m][k] * W[n][k] ---------------
// UNCHANGED from round 2 (bitwise-verified against the np reference).
__global__ __launch_bounds__(256)
void gemm_ff(const float* __restrict__ X, const float* __restrict__ W,
             float* __restrict__ F, int M) {
    const int bx = blockIdx.x;   // n-tile: 0..3
    const int by = blockIdx.y;   // m-tile
    const int tid = threadIdx.x;

    __shared__ float As[32][128];
    __shared__ float Bs[32][128];

    const int tn0 = (tid & 15) * 8;
    const int tm0 = (tid >> 4) * 8;
    float acc[8][8] = {};

    const int am = tid >> 1;
    const int aq = (tid & 1) * 4;

    const float* Xb = X + (size_t)(by * 128 + am) * NIN;
    const float* Wb = W + (size_t)(bx * 128 + am) * NIN;

    for (int k0 = 0; k0 < NIN; k0 += 32) {
        __syncthreads();
#pragma unroll
        for (int i2 = 0; i2 < 4; ++i2) {
            const int q = aq + i2;
            float4 xa = *reinterpret_cast<const float4*>(Xb + k0 + q * 4);
            As[q * 4 + 0][am] = xa.x; As[q * 4 + 1][am] = xa.y;
            As[q * 4 + 2][am] = xa.z; As[q * 4 + 3][am] = xa.w;
            float4 wa = *reinterpret_cast<const float4*>(Wb + k0 + q * 4);
            Bs[q * 4 + 0][am] = wa.x; Bs[q * 4 + 1][am] = wa.y;
            Bs[q * 4 + 2][am] = wa.z; Bs[q * 4 + 3][am] = wa.w;
        }
        __syncthreads();
#pragma unroll 8
        for (int kk = 0; kk < 32; ++kk) {
            float4 a0 = *reinterpret_cast<const float4*>(&As[kk][tm0]);
            float4 a1 = *reinterpret_cast<const float4*>(&As[kk][tm0 + 4]);
            float4 b0 = *reinterpret_cast<const float4*>(&Bs[kk][tn0]);
            float4 b1 = *reinterpret_cast<const float4*>(&Bs[kk][tn0 + 4]);
            const float av[8] = {a0.x, a0.y, a0.z, a0.w, a1.x, a1.y, a1.z, a1.w};
            const float bv[8] = {b0.x, b0.y, b0.z, b0.w, b1.x, b1.y, b1.z, b1.w};
#pragma unroll
            for (int i = 0; i < 8; ++i)
#pragma unroll
                for (int j = 0; j < 8; ++j)
                    acc[i][j] += av[i] * bv[j];
        }
    }

    float* Fo = F + (size_t)(by * 128 + tm0) * NH + bx * 128 + tn0;
#pragma unroll
    for (int i = 0; i < 8; ++i) {
        *reinterpret_cast<float4*>(Fo + (size_t)i * NH) =
            make_float4(acc[i][0], acc[i][1], acc[i][2], acc[i][3]);
        *reinterpret_cast<float4*>(Fo + (size_t)i * NH + 4) =
            make_float4(acc[i][4], acc[i][5], acc[i][6], acc[i][7]);
    }
}

// ---------------- gather tile helpers ---------------------------------------
__device__ __forceinline__ void fill_tile(float (&buf)[TS], const int* lp,
                                          int base, const char* wb) {
#pragma unroll
    for (int i = 0; i < TS; i += 4) {
        const int4 o = *reinterpret_cast<const int4*>(lp + base + i);
        buf[i + 0] = *reinterpret_cast<const float*>(wb + o.x);
        buf[i + 1] = *reinterpret_cast<const float*>(wb + o.y);
        buf[i + 2] = *reinterpret_cast<const float*>(wb + o.z);
        buf[i + 3] = *reinterpret_cast<const float*>(wb + o.w);
    }
}
__device__ __forceinline__ void add_tile(const float (&buf)[TS], float& rec) {
#pragma unroll
    for (int i = 0; i < TS; ++i) rec = __fadd_rn(rec, buf[i]);
}

// ---------------- scan kernel: one WG (512 thr) per batch element -----------
// st layout: [z | v | i | b], each BB*NH floats.
__global__ __launch_bounds__(512, 1)
void lsnn_scan(const float* __restrict__ F, const float* __restrict__ wT,
               const float* __restrict__ z0, const float* __restrict__ v0,
               const float* __restrict__ i0, const float* __restrict__ b0,
               float* __restrict__ out, float* __restrict__ st,
               int t0, int Tc, int first, int last) {
    const int n    = threadIdx.x;        // neuron / column 0..511
    const int b    = blockIdx.x;         // batch
    const int lane = n & 63;
    const int wv   = n >> 6;             // wave 0..7
    const size_t bn = (size_t)b * NH + n;

    __shared__ __align__(16) int lists[2][NH + 2 * TS];  // byte offsets + pad
    __shared__ int cnts[2][8];

    float v, cur, bb, zprev;
    if (first) {
        zprev = z0[bn]; v = v0[bn]; cur = i0[bn]; bb = b0[bn];
    } else {
        zprev = st[0 * BB * NH + bn];
        v     = st[1 * BB * NH + bn];
        cur   = st[2 * BB * NH + bn];
        bb    = st[3 * BB * NH + bn];
    }

    // ---- initial list build (buffer 0), ascending neuron order -------------
    int cnt;
    {
        const unsigned long long m = __ballot(zprev > 0.0f);
        if (lane == 0) cnts[0][wv] = __popcll(m);
        __syncthreads();
        int base = 0, tot = 0;
        for (int q = 0; q < 8; ++q) {
            const int c = cnts[0][q];
            if (q < wv) base += c;
            tot += c;
        }
        if (zprev > 0.0f)
            lists[0][base + __popcll(m & ((1ull << lane) - 1ull))] = n << 11;
        if (n < 2 * TS) lists[0][tot + n] = PADOFF;   // pad region
        __syncthreads();
        cnt = tot;
    }
    int par = 0;

    const char*  wb = reinterpret_cast<const char*>(wT) + (size_t)n * 4;
    const float* Fp = F + (size_t)b * NH + n;
    float* op = out + ((size_t)t0 * BB + b) * NH + n;

    for (int t = 0; t < Tc; ++t) {
        // ---- t.1: prefetch F, elementwise update, ballot --------------------
        const float fval = Fp[(size_t)t * BB * NH];   // consumed after gather
        const float v_dec = __fadd_rn(v, __fmul_rn(KV, __fadd_rn(__fsub_rn(0.0f, v), cur)));
        const float i_dec = __fsub_rn(cur, __fmul_rn(KI, cur));
        const float b_dec = __fadd_rn(bb, __fmul_rn(KB, __fsub_rn(1.0f, bb)));
        const float zn = (__fsub_rn(v_dec, b_dec) > 0.0f) ? 1.0f : 0.0f;
        v  = (zn > 0.0f) ? 0.0f : v_dec;
        bb = __fadd_rn(b_dec, __fmul_rn(zn, KJ));
        op[0] = zn;
        op += (size_t)BB * NH;
        const unsigned long long mm = __ballot(zn > 0.0f);
        if (lane == 0) cnts[par ^ 1][wv] = __popcll(mm);

        // ---- t.2: pipelined serial gather over lists[par] -------------------
        // One ascending __fadd_rn chain per column (bitwise == BLAS).
        float rec = 0.0f;
        if (cnt > 0) {
            const int* lp = lists[par];
            float bufA[TS], bufB[TS];
            fill_tile(bufA, lp, 0, wb);
            int kt = 0;
            for (;;) {
                fill_tile(bufB, lp, kt + TS, wb);   // issue next tile's loads
                add_tile(bufA, rec);                // chain current tile
                kt += TS;
                if (kt >= cnt) break;
                fill_tile(bufA, lp, kt + TS, wb);
                add_tile(bufB, rec);
                kt += TS;
                if (kt >= cnt) break;
            }
        }
        cur = __fadd_rn(__fadd_rn(i_dec, fval), rec);
        zprev = zn;

        __syncthreads();   // B1: cnts[par^1] published; lists[par] drained

        // ---- t.3: build next list (lists[par^1]) ----------------------------
        int base = 0, tot = 0;
        for (int q = 0; q < 8; ++q) {
            const int c = cnts[par ^ 1][q];
            if (q < wv) base += c;
            tot += c;
        }
        if (zn > 0.0f)
            lists[par ^ 1][base + __popcll(mm & ((1ull << lane) - 1ull))] = n << 11;
        if (n < 2 * TS) lists[par ^ 1][tot + n] = PADOFF;
        __syncthreads();   // B2: lists[par^1] ready

        par ^= 1;
        cnt = tot;
    }

    st[0 * BB * NH + bn] = zprev;
    st[1 * BB * NH + bn] = v;
    st[2 * BB * NH + bn] = cur;
    st[3 * BB * NH + bn] = bb;
    if (last) {
        float* tail = out + (size_t)TT * BB * NH;
        tail[0 * BB * NH + bn] = zprev;  // zT
        tail[1 * BB * NH + bn] = v;      // vT
        tail[2 * BB * NH + bn] = cur;    // iT
        tail[3 * BB * NH + bn] = bb;     // bT
    }
}

// ---------------------------------------------------------------------------
extern "C" void kernel_launch(void* const* d_in, const int* in_sizes, int n_in,
                              void* d_out, int out_size, void* d_ws, size_t ws_size,
                              hipStream_t stream) {
    const float* X     = (const float*)d_in[0];
    const float* z0    = (const float*)d_in[1];
    const float* v0    = (const float*)d_in[2];
    const float* i0    = (const float*)d_in[3];
    const float* b0    = (const float*)d_in[4];
    const float* w_in  = (const float*)d_in[5];
    const float* w_rec = (const float*)d_in[6];
    float* out = (float*)d_out;

    char* ws = (char*)d_ws;
    float* wT = (float*)ws;                                    // 1 MB + 2 KB (zero row)
    const size_t wT_bytes = ((size_t)NH * NH + NH) * 4 + 2048; // pad to align
    float* st = (float*)(ws + wT_bytes);                       // 512 KB
    char*  fbase = ws + wT_bytes + (512u << 10);

    const long long per = (long long)BB * NH * 4;              // bytes/step of F
    long long avail = (long long)ws_size - (long long)(wT_bytes + (512u << 10));
    int Tc;
    if (avail >= 2 * per * TT) {
        Tc = TT;
    } else {
        Tc = (int)(avail / (2 * per));
        if (Tc > TT) Tc = TT;
        Tc &= ~1;
        if (Tc < 2) Tc = 2;
    }
    const size_t fbytes = (size_t)Tc * per;
    float* Fb[2] = { (float*)fbase, (float*)(fbase + fbytes) };

    transp512<<<dim3(16, 16), dim3(32, 8), 0, stream>>>(w_rec, wT);
    zrow<<<1, NH, 0, stream>>>(wT);

    int t0 = 0, buf = 0;
    bool firstc = true;
    while (t0 < TT) {
        const int Tcur = (Tc < TT - t0) ? Tc : (TT - t0);
        const int Mc = Tcur * BB;
        gemm_ff<<<dim3(4, Mc / 128), 256, 0, stream>>>(
            X + (size_t)t0 * BB * NIN, w_in, Fb[buf], Mc);
        lsnn_scan<<<dim3(BB), dim3(512), 0, stream>>>(
            Fb[buf], wT, z0, v0, i0, b0, out, st,
            t0, Tcur, firstc ? 1 : 0, (t0 + Tcur >= TT) ? 1 : 0);
        firstc = false;
        buf ^= 1;
        t0 += Tcur;
    }
}